// Round 7
// baseline (230.216 us; speedup 1.0000x reference)
//
#include <hip/hip_runtime.h>

#define N_NODES 50000
#define N_EDGES 800000
#define N_GRAPHS 512
#define ZN N_NODES    // zero-feature pad node (row 50000 of xb/hb, zeroed in k_prep)
#define BCAP 1536     // edges per 64-node bucket; Poisson(1024), P(>1536) ~ 1e-50
#define RCAP 64       // per-node list cap (self+neighbors); P(deg+1>64 | lam=16) ~ 1e-20
#define NBKT 782      // ceil(N_NODES/64) destination buckets
#define EPB  8192     // edges per scatter block (1024 thr x 8)
#define SCB  ((N_EDGES + EPB - 1) / EPB)   // 98 scatter blocks

typedef __bf16 bf16x8 __attribute__((ext_vector_type(8)));
typedef float f32x4 __attribute__((ext_vector_type(4)));
typedef unsigned short u16;
typedef unsigned int u32;

__device__ __forceinline__ u16 f2bf(float f) {
    union { float f; u32 i; } v; v.f = f;
    u32 r = v.i + 0x7fffu + ((v.i >> 16) & 1u);
    return (u16)(r >> 16);
}
__device__ __forceinline__ float bf2f(u16 u) {
    union { u32 i; float f; } v; v.i = ((u32)u) << 16; return v.f;
}

// ---------------- mega prep ----------------
// Two-level binning scatter (r5): LDS histogram per 8192-edge block, one global atomicAdd per
// (block,bucket), direct stores into reserved contiguous runs. Proven: prep fell out of top-5.
__global__ __launch_bounds__(1024)
void k_prep(const int* __restrict__ ei, int* __restrict__ cur, u32* __restrict__ bins,
            const float* __restrict__ X, u16* __restrict__ XB, u16* __restrict__ HB,
            const float* __restrict__ W1a, const float* __restrict__ W1b,
            const float* __restrict__ W2a, const float* __restrict__ W2b,
            u16* __restrict__ T1a, u16* __restrict__ T1b,
            u16* __restrict__ T2a, u16* __restrict__ T2b,
            int E, int n4) {
    __shared__ int lcnt[NBKT];
    __shared__ int lpos[NBKT];
    int bid = blockIdx.x;
    int t = threadIdx.x;
    if (bid < SCB) {
        for (int i = t; i < NBKT; i += 1024) lcnt[i] = 0;
        __syncthreads();
        int e0 = bid * EPB;
        int sarr[8], barr[8], dlar[8];
#pragma unroll
        for (int k = 0; k < 8; ++k) {
            int e = e0 + k * 1024 + t;
            if (e < E) {
                int s = ei[e];
                int d = ei[E + e];
                sarr[k] = s; barr[k] = d >> 6; dlar[k] = d & 63;
                atomicAdd(&lcnt[d >> 6], 1);
            } else {
                barr[k] = -1; sarr[k] = 0; dlar[k] = 0;
            }
        }
        __syncthreads();
        for (int i = t; i < NBKT; i += 1024) {
            int c = lcnt[i];
            lpos[i] = (c > 0) ? atomicAdd(&cur[i * 32], c) : 0;
        }
        __syncthreads();
#pragma unroll
        for (int k = 0; k < 8; ++k) {
            if (barr[k] >= 0) {
                int p = atomicAdd(&lpos[barr[k]], 1);
                if (p < BCAP)
                    bins[(size_t)barr[k] * BCAP + p] = (((u32)dlar[k]) << 16) | (u32)sarr[k];
            }
        }
    } else if (bid < SCB + 1563) {
        int i = (bid - SCB) * 1024 + t;
        if (i < n4) {
            float4 v = ((const float4*)X)[i];
            ushort4 o;
            o.x = f2bf(v.x); o.y = f2bf(v.y); o.z = f2bf(v.z); o.w = f2bf(v.w);
            ((ushort4*)XB)[i] = o;
        }
    } else if (bid < SCB + 1563 + 64) {
        int b2 = bid - (SCB + 1563);            // 0..63
        int widx = b2 >> 4;                     // which weight
        int i = (b2 & 15) * 1024 + t;           // 0..16383
        const float* W = widx == 0 ? W1a : widx == 1 ? W1b : widx == 2 ? W2a : W2b;
        u16* T = widx == 0 ? T1a : widx == 1 ? T1b : widx == 2 ? T2a : T2b;
        int k = i >> 7, n = i & 127;
        T[n * 128 + k] = f2bf(W[k * 128 + n]);
    } else {
        // zero the pad node row (index ZN) in both feature tables
        if (t < 64)       ((u32*)XB)[(size_t)ZN * 64 + t]        = 0u;
        else if (t < 128) ((u32*)HB)[(size_t)ZN * 64 + (t - 64)] = 0u;
    }
}

// ---------------- fused GIN layer: LDS list build + pipelined gather + 2-stage MFMA MLP ----------------
// r7: W fragments read directly from global (L2-hot 32KB shared by all blocks) instead of LDS
// staging. LDS 56.5K -> ~25K => 3 blocks/CU (was 2): gather phases of one block cover MFMA/build
// phases of others, keeping the ~2TB/s fetch stream saturated.
// W fragment address (derived by inverting the old swizzled store/read XOR):
//   frag(n, kt, q) = WT + n*128 + (kt*4+q)*8   (8 consecutive bf16)

#define STAGE16(BUF, CI, CJ)                                            \
    _Pragma("unroll")                                                   \
    for (int u = 0; u < 16; ++u) {                                      \
        u32 nb = (u32)smI[wv * 8 + (CI)][(CJ) + u];                     \
        BUF[u] = X2[(nb << 6) + lane];                                  \
    }

#define ACCUM16(BUF)                                                    \
    _Pragma("unroll")                                                   \
    for (int u = 0; u < 16; ++u) {                                      \
        ax += bf2f((u16)(BUF[u] & 0xffff));                             \
        ay += bf2f((u16)(BUF[u] >> 16));                                \
    }

#define FINROW(CI) {                                                    \
        int r = wv * 8 + (CI);                                          \
        smZu[(r * 16 + ((lane >> 2) ^ (r & 15))) * 4 + (lane & 3)] =    \
            (((u32)f2bf(ay)) << 16) | (u32)f2bf(ax);                    \
        ax = 0.f; ay = 0.f;                                             \
    }

// init smI rows to ZN with self at col0, deg=1; append bucket edges; then pipelined gather.
// smI row = 64 u16 = 8 uint4 -> uint4 idx tid maps to (row = tid>>3, col4 = tid&7).
#define AGG_PHASE()                                                                  \
    {                                                                                \
        const u32 fill = 0xC350C350u;  /* ZN=50000=0xC350 pair */                    \
        int r = tid >> 3, c = tid & 7;                                               \
        uint4 v4 = make_uint4(fill, fill, fill, fill);                               \
        if (c == 0) {                                                                \
            int gr = row0 + r;                                                       \
            v4.x = (fill & 0xffff0000u) | (u32)((gr < N) ? gr : ZN);                 \
        }                                                                            \
        ((uint4*)smI)[tid] = v4;                                                     \
        if (tid < 64) ldsCnt[tid] = 1;                                               \
    }                                                                                \
    __syncthreads();                                                                 \
    {                                                                                \
        int ecnt = cur[blockIdx.x * 32];                                             \
        if (ecnt > BCAP) ecnt = BCAP;                                                \
        const u32* myb = bins + (size_t)blockIdx.x * BCAP;                           \
        for (int i = tid; i < ecnt; i += 512) {                                      \
            u32 v = myb[i];                                                          \
            int dl = v >> 16;                                                        \
            int pos = atomicAdd(&ldsCnt[dl], 1);                                     \
            if (pos < RCAP) smI[dl][pos] = (u16)(v & 0xffff);                        \
        }                                                                            \
    }                                                                                \
    __syncthreads();                                                                 \
    int degv = 0;                                                                    \
    if (lane < 8) {                                                                  \
        int d = ldsCnt[wv * 8 + lane];                                               \
        degv = d > RCAP ? RCAP : d;                                                  \
    }                                                                                \
    {                                                                                \
        float ax = 0.f, ay = 0.f;                                                    \
        u32 bufA[16], bufB[16];                                                      \
        int ci = 0, cj = 0;                                                          \
        int de = __builtin_amdgcn_readlane(degv, 0);                                 \
        STAGE16(bufA, 0, 0);                                                         \
        for (;;) {                                                                   \
            int ni = ci, nj = cj + 16;                                               \
            if (nj >= de) { ni = ci + 1; nj = 0; }                                   \
            int have = (ni < 8);                                                     \
            if (have) { de = __builtin_amdgcn_readlane(degv, ni);                    \
                        STAGE16(bufB, ni, nj); }                                     \
            ACCUM16(bufA);                                                           \
            if (nj == 0) FINROW(ci);                                                 \
            if (!have) break;                                                        \
            ci = ni; cj = nj;                                                        \
            ni = ci; nj = cj + 16;                                                   \
            if (nj >= de) { ni = ci + 1; nj = 0; }                                   \
            have = (ni < 8);                                                         \
            if (have) { de = __builtin_amdgcn_readlane(degv, ni);                    \
                        STAGE16(bufA, ni, nj); }                                     \
            ACCUM16(bufB);                                                           \
            if (nj == 0) FINROW(ci);                                                 \
            if (!have) break;                                                        \
            ci = ni; cj = nj;                                                        \
        }                                                                            \
    }

__global__ __launch_bounds__(512, 6)
void k_gin1(const u16* __restrict__ X, const int* __restrict__ cur,
            const u32* __restrict__ bins,
            const u16* __restrict__ WaT, const float* __restrict__ ba,
            const u16* __restrict__ WbT, const float* __restrict__ bb,
            u16* __restrict__ H, int N) {
    __shared__ u16 smZ[64 * 128];       // agg tile (swizzled), later mid tile
    __shared__ u16 smI[64][RCAP];       // per-row neighbor lists (self + edges, ZN-padded)
    __shared__ int ldsCnt[64];
    uint4* smZ4 = (uint4*)smZ;
    u32* smZu = (u32*)smZ;

    const int tid = threadIdx.x;
    const int lane = tid & 63, wv = tid >> 6;
    const int q = lane >> 4, m = lane & 15;
    const int ws = wv & 3, wc = wv >> 2;     // wave = (row strip 0..3) x (col half 0..1)
    const int row0 = blockIdx.x * 64;
    const u32* X2 = (const u32*)X;

    AGG_PHASE();
    __syncthreads();

    f32x4 acc[4];
#pragma unroll
    for (int nt = 0; nt < 4; ++nt) acc[nt] = (f32x4){0.f, 0.f, 0.f, 0.f};
#pragma unroll
    for (int kt = 0; kt < 4; ++kt) {
        int r = ws * 16 + m;
        bf16x8 a = *(const bf16x8*)(smZ4 + (r * 16 + ((kt * 4 + q) ^ (r & 15))));
#pragma unroll
        for (int nt = 0; nt < 4; ++nt) {
            int n = (wc * 4 + nt) * 16 + m;
            bf16x8 bfr = *(const bf16x8*)(WaT + n * 128 + (kt * 4 + q) * 8);
            acc[nt] = __builtin_amdgcn_mfma_f32_16x16x32_bf16(a, bfr, acc[nt], 0, 0, 0);
        }
    }
    __syncthreads();

#pragma unroll
    for (int nt = 0; nt < 4; ++nt) {         // mid tile: relu(acc+ba), swizzled
        int col = (wc * 4 + nt) * 16 + m;
        float bias = ba[col];
        int c4 = col >> 3, ci8 = col & 7;
#pragma unroll
        for (int r2 = 0; r2 < 4; ++r2) {
            int row = ws * 16 + q * 4 + r2;  // C-layout: row=(lane>>4)*4+reg
            float x = acc[nt][r2] + bias;
            x = x > 0.f ? x : 0.f;
            smZ[(row * 16 + (c4 ^ (row & 15))) * 8 + ci8] = f2bf(x);
        }
    }
    __syncthreads();

    f32x4 acc2[4];
#pragma unroll
    for (int nt = 0; nt < 4; ++nt) acc2[nt] = (f32x4){0.f, 0.f, 0.f, 0.f};
#pragma unroll
    for (int kt = 0; kt < 4; ++kt) {
        int r = ws * 16 + m;
        bf16x8 a = *(const bf16x8*)(smZ4 + (r * 16 + ((kt * 4 + q) ^ (r & 15))));
#pragma unroll
        for (int nt = 0; nt < 4; ++nt) {
            int n = (wc * 4 + nt) * 16 + m;
            bf16x8 bfr = *(const bf16x8*)(WbT + n * 128 + (kt * 4 + q) * 8);
            acc2[nt] = __builtin_amdgcn_mfma_f32_16x16x32_bf16(a, bfr, acc2[nt], 0, 0, 0);
        }
    }
#pragma unroll
    for (int nt = 0; nt < 4; ++nt) {
        int col = (wc * 4 + nt) * 16 + m;
        float bias = bb[col];
#pragma unroll
        for (int r2 = 0; r2 < 4; ++r2) {
            int row = row0 + ws * 16 + q * 4 + r2;
            if (row < N) {
                float x = acc2[nt][r2] + bias;
                H[(size_t)row * 128 + col] = f2bf(x > 0.f ? x : 0.f);
            }
        }
    }
}

__global__ __launch_bounds__(512, 6)
void k_gin2(const u16* __restrict__ X, const int* __restrict__ cur,
            const u32* __restrict__ bins,
            const u16* __restrict__ WaT, const float* __restrict__ ba,
            const u16* __restrict__ WbT, const float* __restrict__ bb,
            const int* __restrict__ batch, float* __restrict__ G, int N) {
    __shared__ u16 smZ[64 * 128];
    __shared__ u16 smI[64][RCAP];
    __shared__ int ldsCnt[64];
    __shared__ int sb[64];
    uint4* smZ4 = (uint4*)smZ;
    u32* smZu = (u32*)smZ;

    const int tid = threadIdx.x;
    const int lane = tid & 63, wv = tid >> 6;
    const int q = lane >> 4, m = lane & 15;
    const int ws = wv & 3, wc = wv >> 2;
    const int row0 = blockIdx.x * 64;
    const u32* X2 = (const u32*)X;

    if (tid >= 448 && tid < 512) {  // last wave loads batch ids (others do smI init)
        int t = tid - 448;
        sb[t] = (row0 + t < N) ? batch[row0 + t] : -1;
    }

    AGG_PHASE();
    __syncthreads();

    f32x4 acc[4];
#pragma unroll
    for (int nt = 0; nt < 4; ++nt) acc[nt] = (f32x4){0.f, 0.f, 0.f, 0.f};
#pragma unroll
    for (int kt = 0; kt < 4; ++kt) {
        int r = ws * 16 + m;
        bf16x8 a = *(const bf16x8*)(smZ4 + (r * 16 + ((kt * 4 + q) ^ (r & 15))));
#pragma unroll
        for (int nt = 0; nt < 4; ++nt) {
            int n = (wc * 4 + nt) * 16 + m;
            bf16x8 bfr = *(const bf16x8*)(WaT + n * 128 + (kt * 4 + q) * 8);
            acc[nt] = __builtin_amdgcn_mfma_f32_16x16x32_bf16(a, bfr, acc[nt], 0, 0, 0);
        }
    }
    __syncthreads();

#pragma unroll
    for (int nt = 0; nt < 4; ++nt) {
        int col = (wc * 4 + nt) * 16 + m;
        float bias = ba[col];
        int c4 = col >> 3, ci8 = col & 7;
#pragma unroll
        for (int r2 = 0; r2 < 4; ++r2) {
            int row = ws * 16 + q * 4 + r2;
            float x = acc[nt][r2] + bias;
            x = x > 0.f ? x : 0.f;
            smZ[(row * 16 + (c4 ^ (row & 15))) * 8 + ci8] = f2bf(x);
        }
    }
    __syncthreads();

    f32x4 acc2[4];
#pragma unroll
    for (int nt = 0; nt < 4; ++nt) acc2[nt] = (f32x4){0.f, 0.f, 0.f, 0.f};
#pragma unroll
    for (int kt = 0; kt < 4; ++kt) {
        int r = ws * 16 + m;
        bf16x8 a = *(const bf16x8*)(smZ4 + (r * 16 + ((kt * 4 + q) ^ (r & 15))));
#pragma unroll
        for (int nt = 0; nt < 4; ++nt) {
            int n = (wc * 4 + nt) * 16 + m;
            bf16x8 bfr = *(const bf16x8*)(WbT + n * 128 + (kt * 4 + q) * 8);
            acc2[nt] = __builtin_amdgcn_mfma_f32_16x16x32_bf16(a, bfr, acc2[nt], 0, 0, 0);
        }
    }
    // epilogue: H2 tile (bf16) into LDS rows, plain row-major
#pragma unroll
    for (int nt = 0; nt < 4; ++nt) {
        int col = (wc * 4 + nt) * 16 + m;
        float bias = bb[col];
#pragma unroll
        for (int r2 = 0; r2 < 4; ++r2) {
            int row = ws * 16 + q * 4 + r2;
            float x = acc2[nt][r2] + bias;
            smZ[row * 128 + col] = f2bf(x > 0.f ? x : 0.f);
        }
    }
    __syncthreads();
    // segmented pool: thread (col, quarter) scans 16 sorted rows, one atomic per run
    {
        int col = tid & 127, quarter = tid >> 7;
        int rbeg = quarter * 16, rend = rbeg + 16;
        float run = 0.f; int curg = -1;
        for (int r = rbeg; r < rend; ++r) {
            int gg = sb[r];
            if (gg < 0) break;
            if (gg != curg) {
                if (curg >= 0) atomicAdd(&G[curg * 128 + col], run);
                run = 0.f; curg = gg;
            }
            run += bf2f(smZ[r * 128 + col]);
        }
        if (curg >= 0) atomicAdd(&G[curg * 128 + col], run);
    }
}

// ---------------- final FC: out = relu(g @ Wfc + bfc) ----------------
__global__ void k_fc(const float* __restrict__ G, const float* __restrict__ W,
                     const float* __restrict__ bias, float* __restrict__ O) {
    __shared__ float gs[128];
    int t = threadIdx.x, gidx = blockIdx.x;
    gs[t] = G[gidx * 128 + t];
    __syncthreads();
    float acc = bias[t];
    for (int k = 0; k < 128; ++k)
        acc += gs[k] * W[k * 128 + t];
    acc = acc > 0.f ? acc : 0.f;
    O[gidx * 128 + t] = acc;
}

extern "C" void kernel_launch(void* const* d_in, const int* in_sizes, int n_in,
                              void* d_out, int out_size, void* d_ws, size_t ws_size,
                              hipStream_t stream) {
    const int N = N_NODES, E = N_EDGES, NG = N_GRAPHS;

    const float* x   = (const float*)d_in[0];
    const int* ei    = (const int*)d_in[1];
    const int* batch = (const int*)d_in[2];
    const float* W1a = (const float*)d_in[3];
    const float* b1a = (const float*)d_in[4];
    const float* W1b = (const float*)d_in[5];
    const float* b1b = (const float*)d_in[6];
    const float* W2a = (const float*)d_in[7];
    const float* b2a = (const float*)d_in[8];
    const float* W2b = (const float*)d_in[9];
    const float* b2b = (const float*)d_in[10];
    const float* Wfc = (const float*)d_in[11];
    const float* bfc = (const float*)d_in[12];
    float* out = (float*)d_out;

    char* w = (char*)d_ws;
    int* cur    = (int*)(w + 0x0000000);   // 782 cursors, 128B apart -> 100KB
    float* g    = (float*)(w + 0x0019000); // 256KB — adjacent to cur: one memset
    u32* bins   = (u32*)(w + 0x0060000);   // 782 x 1536 x 4B = 4.6MB edge buckets
    u16* xb     = (u16*)(w + 0x0500000);   // 12.8MB + pad row (X in bf16)
    u16* hb     = (u16*)(w + 0x1200000);   // 12.8MB + pad row (H table)
    u16* T1a    = (u16*)(w + 0x1F00000);   // 32KB each
    u16* T1b    = (u16*)(w + 0x1F08000);
    u16* T2a    = (u16*)(w + 0x1F10000);
    u16* T2b    = (u16*)(w + 0x1F18000);

    (void)hipMemsetAsync(w, 0, 0x59000, stream);   // cur + g in one shot

    const int n4 = N * 128 / 4;
    const int PREPB = SCB + 1563 + 64 + 1;   // scatter + convert + transpose + pad
    k_prep<<<PREPB, 1024, 0, stream>>>(ei, cur, bins, x, xb, hb, W1a, W1b, W2a, W2b,
                                       T1a, T1b, T2a, T2b, E, n4);

    const int GINB = (N + 63) / 64;          // 782 blocks = buckets, 3/CU resident

    k_gin1<<<GINB, 512, 0, stream>>>(xb, cur, bins, T1a, b1a, T1b, b1b, hb, N);
    k_gin2<<<GINB, 512, 0, stream>>>(hb, cur, bins, T2a, b2a, T2b, b2b, batch, g, N);

    k_fc<<<NG, 128, 0, stream>>>(g, Wfc, bfc, out);
}

// Round 8
// 196.850 us; speedup vs baseline: 1.1695x; 1.1695x over previous
//
#include <hip/hip_runtime.h>

#define N_NODES 50000
#define N_EDGES 800000
#define N_GRAPHS 512
#define ZN N_NODES    // zero-feature pad node (row 50000 of xb/hb, zeroed in k_prep)
#define BCAP 1536     // edges per 64-node bucket; Poisson(1024), P(>1536) ~ 1e-50
#define RCAP 64       // per-node list cap (self+neighbors); P(deg+1>64 | lam=16) ~ 1e-20
#define NBKT 782      // ceil(N_NODES/64) destination buckets
#define EPB  8192     // edges per scatter block (1024 thr x 8)
#define SCB  ((N_EDGES + EPB - 1) / EPB)   // 98 scatter blocks

typedef __bf16 bf16x8 __attribute__((ext_vector_type(8)));
typedef float f32x4 __attribute__((ext_vector_type(4)));
typedef unsigned short u16;
typedef unsigned int u32;

__device__ __forceinline__ u16 f2bf(float f) {
    union { float f; u32 i; } v; v.f = f;
    u32 r = v.i + 0x7fffu + ((v.i >> 16) & 1u);
    return (u16)(r >> 16);
}
__device__ __forceinline__ float bf2f(u16 u) {
    union { u32 i; float f; } v; v.i = ((u32)u) << 16; return v.f;
}

// ---------------- mega prep ----------------
// Two-level binning scatter (r5): LDS histogram per 8192-edge block, one global atomicAdd per
// (block,bucket), direct stores into reserved contiguous runs.
// r8: convert widened to 16B/thread (float4 x2 -> uint4 of 8 bf16): 1563 -> 782 convert blocks,
// prep grid 1726 -> 945 blocks (3.4 -> 1.85 dispatch rounds) to cut prep makespan.
__global__ __launch_bounds__(1024)
void k_prep(const int* __restrict__ ei, int* __restrict__ cur, u32* __restrict__ bins,
            const float* __restrict__ X, u16* __restrict__ XB, u16* __restrict__ HB,
            const float* __restrict__ W1a, const float* __restrict__ W1b,
            const float* __restrict__ W2a, const float* __restrict__ W2b,
            u16* __restrict__ T1a, u16* __restrict__ T1b,
            u16* __restrict__ T2a, u16* __restrict__ T2b,
            int E, int n8) {
    __shared__ int lcnt[NBKT];
    __shared__ int lpos[NBKT];
    int bid = blockIdx.x;
    int t = threadIdx.x;
    if (bid < SCB) {
        for (int i = t; i < NBKT; i += 1024) lcnt[i] = 0;
        __syncthreads();
        int e0 = bid * EPB;
        int sarr[8], barr[8], dlar[8];
#pragma unroll
        for (int k = 0; k < 8; ++k) {
            int e = e0 + k * 1024 + t;
            if (e < E) {
                int s = ei[e];
                int d = ei[E + e];
                sarr[k] = s; barr[k] = d >> 6; dlar[k] = d & 63;
                atomicAdd(&lcnt[d >> 6], 1);
            } else {
                barr[k] = -1; sarr[k] = 0; dlar[k] = 0;
            }
        }
        __syncthreads();
        for (int i = t; i < NBKT; i += 1024) {
            int c = lcnt[i];
            lpos[i] = (c > 0) ? atomicAdd(&cur[i * 32], c) : 0;
        }
        __syncthreads();
#pragma unroll
        for (int k = 0; k < 8; ++k) {
            if (barr[k] >= 0) {
                int p = atomicAdd(&lpos[barr[k]], 1);
                if (p < BCAP)
                    bins[(size_t)barr[k] * BCAP + p] = (((u32)dlar[k]) << 16) | (u32)sarr[k];
            }
        }
    } else if (bid < SCB + 782) {
        int i = (bid - SCB) * 1024 + t;        // one 16B output (8 bf16) per thread
        if (i < n8) {
            float4 v0 = ((const float4*)X)[i * 2];
            float4 v1 = ((const float4*)X)[i * 2 + 1];
            uint4 o;
            o.x = (u32)f2bf(v0.x) | (((u32)f2bf(v0.y)) << 16);
            o.y = (u32)f2bf(v0.z) | (((u32)f2bf(v0.w)) << 16);
            o.z = (u32)f2bf(v1.x) | (((u32)f2bf(v1.y)) << 16);
            o.w = (u32)f2bf(v1.z) | (((u32)f2bf(v1.w)) << 16);
            ((uint4*)XB)[i] = o;
        }
    } else if (bid < SCB + 782 + 64) {
        int b2 = bid - (SCB + 782);             // 0..63
        int widx = b2 >> 4;                     // which weight
        int i = (b2 & 15) * 1024 + t;           // 0..16383
        const float* W = widx == 0 ? W1a : widx == 1 ? W1b : widx == 2 ? W2a : W2b;
        u16* T = widx == 0 ? T1a : widx == 1 ? T1b : widx == 2 ? T2a : T2b;
        int k = i >> 7, n = i & 127;
        T[n * 128 + k] = f2bf(W[k * 128 + n]);
    } else {
        // zero the pad node row (index ZN) in both feature tables
        if (t < 64)       ((u32*)XB)[(size_t)ZN * 64 + t]        = 0u;
        else if (t < 128) ((u32*)HB)[(size_t)ZN * 64 + (t - 64)] = 0u;
    }
}

// ---------------- fused GIN layer: LDS list build + pipelined gather + 2-stage MFMA MLP ----------------
// 64-row tile, 512 threads (8 waves), 2 blocks/CU. Wave aggregates 8 rows via flat chunk stream
// (16 nbrs/chunk, A/B double-buffered loads, next chunk issued before current accum).
// W stays in LDS (r7 lesson: W-from-global puts MFMA operands on vmcnt -> every MFMA waitcnt
// drains the gather prefetch queue; LDS keeps them on lgkmcnt, decoupled. 2.04 vs 1.46 TB/s).

#define STAGE16(BUF, CI, CJ)                                            \
    _Pragma("unroll")                                                   \
    for (int u = 0; u < 16; ++u) {                                      \
        u32 nb = (u32)smI[wv * 8 + (CI)][(CJ) + u];                     \
        BUF[u] = X2[(nb << 6) + lane];                                  \
    }

#define ACCUM16(BUF)                                                    \
    _Pragma("unroll")                                                   \
    for (int u = 0; u < 16; ++u) {                                      \
        ax += bf2f((u16)(BUF[u] & 0xffff));                             \
        ay += bf2f((u16)(BUF[u] >> 16));                                \
    }

#define FINROW(CI) {                                                    \
        int r = wv * 8 + (CI);                                          \
        smZu[(r * 16 + ((lane >> 2) ^ (r & 15))) * 4 + (lane & 3)] =    \
            (((u32)f2bf(ay)) << 16) | (u32)f2bf(ax);                    \
        ax = 0.f; ay = 0.f;                                             \
    }

// init smI rows to ZN with self at col0, deg=1; append bucket edges; then pipelined gather.
// smI row = 64 u16 = 8 uint4 -> uint4 idx tid maps to (row = tid>>3, col4 = tid&7).
#define AGG_PHASE()                                                                  \
    {                                                                                \
        const u32 fill = 0xC350C350u;  /* ZN=50000=0xC350 pair */                    \
        int r = tid >> 3, c = tid & 7;                                               \
        uint4 v4 = make_uint4(fill, fill, fill, fill);                               \
        if (c == 0) {                                                                \
            int gr = row0 + r;                                                       \
            v4.x = (fill & 0xffff0000u) | (u32)((gr < N) ? gr : ZN);                 \
        }                                                                            \
        ((uint4*)smI)[tid] = v4;                                                     \
        if (tid < 64) ldsCnt[tid] = 1;                                               \
    }                                                                                \
    __syncthreads();                                                                 \
    {                                                                                \
        int ecnt = cur[blockIdx.x * 32];                                             \
        if (ecnt > BCAP) ecnt = BCAP;                                                \
        const u32* myb = bins + (size_t)blockIdx.x * BCAP;                           \
        for (int i = tid; i < ecnt; i += 512) {                                      \
            u32 v = myb[i];                                                          \
            int dl = v >> 16;                                                        \
            int pos = atomicAdd(&ldsCnt[dl], 1);                                     \
            if (pos < RCAP) smI[dl][pos] = (u16)(v & 0xffff);                        \
        }                                                                            \
    }                                                                                \
    __syncthreads();                                                                 \
    int degv = 0;                                                                    \
    if (lane < 8) {                                                                  \
        int d = ldsCnt[wv * 8 + lane];                                               \
        degv = d > RCAP ? RCAP : d;                                                  \
    }                                                                                \
    {                                                                                \
        float ax = 0.f, ay = 0.f;                                                    \
        u32 bufA[16], bufB[16];                                                      \
        int ci = 0, cj = 0;                                                          \
        int de = __builtin_amdgcn_readlane(degv, 0);                                 \
        STAGE16(bufA, 0, 0);                                                         \
        for (;;) {                                                                   \
            int ni = ci, nj = cj + 16;                                               \
            if (nj >= de) { ni = ci + 1; nj = 0; }                                   \
            int have = (ni < 8);                                                     \
            if (have) { de = __builtin_amdgcn_readlane(degv, ni);                    \
                        STAGE16(bufB, ni, nj); }                                     \
            ACCUM16(bufA);                                                           \
            if (nj == 0) FINROW(ci);                                                 \
            if (!have) break;                                                        \
            ci = ni; cj = nj;                                                        \
            ni = ci; nj = cj + 16;                                                   \
            if (nj >= de) { ni = ci + 1; nj = 0; }                                   \
            have = (ni < 8);                                                         \
            if (have) { de = __builtin_amdgcn_readlane(degv, ni);                    \
                        STAGE16(bufA, ni, nj); }                                     \
            ACCUM16(bufB);                                                           \
            if (nj == 0) FINROW(ci);                                                 \
            if (!have) break;                                                        \
            ci = ni; cj = nj;                                                        \
        }                                                                            \
    }

__global__ __launch_bounds__(512, 4)
void k_gin1(const u16* __restrict__ X, const int* __restrict__ cur,
            const u32* __restrict__ bins,
            const u16* __restrict__ WaT, const float* __restrict__ ba,
            const u16* __restrict__ WbT, const float* __restrict__ bb,
            u16* __restrict__ H, int N) {
    __shared__ u16 smZ[64 * 128];       // agg tile (swizzled), later mid tile
    __shared__ u16 smW[128 * 128];      // Wa, later Wb
    __shared__ u16 smI[64][RCAP];       // per-row neighbor lists (self + edges, ZN-padded)
    __shared__ int ldsCnt[64];
    uint4* smZ4 = (uint4*)smZ;
    uint4* smW4 = (uint4*)smW;
    u32* smZu = (u32*)smZ;

    const int tid = threadIdx.x;
    const int lane = tid & 63, wv = tid >> 6;
    const int q = lane >> 4, m = lane & 15;
    const int ws = wv & 3, wc = wv >> 2;     // wave = (row strip 0..3) x (col half 0..1)
    const int row0 = blockIdx.x * 64;
    const u32* X2 = (const u32*)X;

    for (int i = tid; i < 2048; i += 512) {  // stage Wa (swizzled), hidden under agg
        int r = i >> 4, c4 = i & 15;
        smW4[r * 16 + (c4 ^ (r & 15))] = ((const uint4*)WaT)[i];
    }

    AGG_PHASE();
    __syncthreads();

    f32x4 acc[4];
#pragma unroll
    for (int nt = 0; nt < 4; ++nt) acc[nt] = (f32x4){0.f, 0.f, 0.f, 0.f};
#pragma unroll
    for (int kt = 0; kt < 4; ++kt) {
        int r = ws * 16 + m;
        bf16x8 a = *(const bf16x8*)(smZ4 + (r * 16 + ((kt * 4 + q) ^ (r & 15))));
#pragma unroll
        for (int nt = 0; nt < 4; ++nt) {
            int n = (wc * 4 + nt) * 16 + m;
            bf16x8 bfr = *(const bf16x8*)(smW4 + (n * 16 + ((kt * 4 + q) ^ (n & 15))));
            acc[nt] = __builtin_amdgcn_mfma_f32_16x16x32_bf16(a, bfr, acc[nt], 0, 0, 0);
        }
    }
    __syncthreads();

    for (int i = tid; i < 2048; i += 512) {  // stage Wb
        int r = i >> 4, c4 = i & 15;
        smW4[r * 16 + (c4 ^ (r & 15))] = ((const uint4*)WbT)[i];
    }
#pragma unroll
    for (int nt = 0; nt < 4; ++nt) {         // mid tile: relu(acc+ba), swizzled
        int col = (wc * 4 + nt) * 16 + m;
        float bias = ba[col];
        int c4 = col >> 3, ci8 = col & 7;
#pragma unroll
        for (int r2 = 0; r2 < 4; ++r2) {
            int row = ws * 16 + q * 4 + r2;  // C-layout: row=(lane>>4)*4+reg
            float x = acc[nt][r2] + bias;
            x = x > 0.f ? x : 0.f;
            smZ[(row * 16 + (c4 ^ (row & 15))) * 8 + ci8] = f2bf(x);
        }
    }
    __syncthreads();

    f32x4 acc2[4];
#pragma unroll
    for (int nt = 0; nt < 4; ++nt) acc2[nt] = (f32x4){0.f, 0.f, 0.f, 0.f};
#pragma unroll
    for (int kt = 0; kt < 4; ++kt) {
        int r = ws * 16 + m;
        bf16x8 a = *(const bf16x8*)(smZ4 + (r * 16 + ((kt * 4 + q) ^ (r & 15))));
#pragma unroll
        for (int nt = 0; nt < 4; ++nt) {
            int n = (wc * 4 + nt) * 16 + m;
            bf16x8 bfr = *(const bf16x8*)(smW4 + (n * 16 + ((kt * 4 + q) ^ (n & 15))));
            acc2[nt] = __builtin_amdgcn_mfma_f32_16x16x32_bf16(a, bfr, acc2[nt], 0, 0, 0);
        }
    }
#pragma unroll
    for (int nt = 0; nt < 4; ++nt) {
        int col = (wc * 4 + nt) * 16 + m;
        float bias = bb[col];
#pragma unroll
        for (int r2 = 0; r2 < 4; ++r2) {
            int row = row0 + ws * 16 + q * 4 + r2;
            if (row < N) {
                float x = acc2[nt][r2] + bias;
                H[(size_t)row * 128 + col] = f2bf(x > 0.f ? x : 0.f);
            }
        }
    }
}

__global__ __launch_bounds__(512, 4)
void k_gin2(const u16* __restrict__ X, const int* __restrict__ cur,
            const u32* __restrict__ bins,
            const u16* __restrict__ WaT, const float* __restrict__ ba,
            const u16* __restrict__ WbT, const float* __restrict__ bb,
            const int* __restrict__ batch, float* __restrict__ G, int N) {
    __shared__ u16 smZ[64 * 128];
    __shared__ u16 smW[128 * 128];
    __shared__ u16 smI[64][RCAP];
    __shared__ int ldsCnt[64];
    __shared__ int sb[64];
    uint4* smZ4 = (uint4*)smZ;
    uint4* smW4 = (uint4*)smW;
    u32* smZu = (u32*)smZ;

    const int tid = threadIdx.x;
    const int lane = tid & 63, wv = tid >> 6;
    const int q = lane >> 4, m = lane & 15;
    const int ws = wv & 3, wc = wv >> 2;
    const int row0 = blockIdx.x * 64;
    const u32* X2 = (const u32*)X;

    if (tid >= 448 && tid < 512) {  // last wave loads batch ids (others do W/smI init)
        int t = tid - 448;
        sb[t] = (row0 + t < N) ? batch[row0 + t] : -1;
    }

    for (int i = tid; i < 2048; i += 512) {
        int r = i >> 4, c4 = i & 15;
        smW4[r * 16 + (c4 ^ (r & 15))] = ((const uint4*)WaT)[i];
    }

    AGG_PHASE();
    __syncthreads();

    f32x4 acc[4];
#pragma unroll
    for (int nt = 0; nt < 4; ++nt) acc[nt] = (f32x4){0.f, 0.f, 0.f, 0.f};
#pragma unroll
    for (int kt = 0; kt < 4; ++kt) {
        int r = ws * 16 + m;
        bf16x8 a = *(const bf16x8*)(smZ4 + (r * 16 + ((kt * 4 + q) ^ (r & 15))));
#pragma unroll
        for (int nt = 0; nt < 4; ++nt) {
            int n = (wc * 4 + nt) * 16 + m;
            bf16x8 bfr = *(const bf16x8*)(smW4 + (n * 16 + ((kt * 4 + q) ^ (n & 15))));
            acc[nt] = __builtin_amdgcn_mfma_f32_16x16x32_bf16(a, bfr, acc[nt], 0, 0, 0);
        }
    }
    __syncthreads();

    for (int i = tid; i < 2048; i += 512) {
        int r = i >> 4, c4 = i & 15;
        smW4[r * 16 + (c4 ^ (r & 15))] = ((const uint4*)WbT)[i];
    }
#pragma unroll
    for (int nt = 0; nt < 4; ++nt) {
        int col = (wc * 4 + nt) * 16 + m;
        float bias = ba[col];
        int c4 = col >> 3, ci8 = col & 7;
#pragma unroll
        for (int r2 = 0; r2 < 4; ++r2) {
            int row = ws * 16 + q * 4 + r2;
            float x = acc[nt][r2] + bias;
            x = x > 0.f ? x : 0.f;
            smZ[(row * 16 + (c4 ^ (row & 15))) * 8 + ci8] = f2bf(x);
        }
    }
    __syncthreads();

    f32x4 acc2[4];
#pragma unroll
    for (int nt = 0; nt < 4; ++nt) acc2[nt] = (f32x4){0.f, 0.f, 0.f, 0.f};
#pragma unroll
    for (int kt = 0; kt < 4; ++kt) {
        int r = ws * 16 + m;
        bf16x8 a = *(const bf16x8*)(smZ4 + (r * 16 + ((kt * 4 + q) ^ (r & 15))));
#pragma unroll
        for (int nt = 0; nt < 4; ++nt) {
            int n = (wc * 4 + nt) * 16 + m;
            bf16x8 bfr = *(const bf16x8*)(smW4 + (n * 16 + ((kt * 4 + q) ^ (n & 15))));
            acc2[nt] = __builtin_amdgcn_mfma_f32_16x16x32_bf16(a, bfr, acc2[nt], 0, 0, 0);
        }
    }
    // epilogue: H2 tile (bf16) into LDS rows, plain row-major
#pragma unroll
    for (int nt = 0; nt < 4; ++nt) {
        int col = (wc * 4 + nt) * 16 + m;
        float bias = bb[col];
#pragma unroll
        for (int r2 = 0; r2 < 4; ++r2) {
            int row = ws * 16 + q * 4 + r2;
            float x = acc2[nt][r2] + bias;
            smZ[row * 128 + col] = f2bf(x > 0.f ? x : 0.f);
        }
    }
    __syncthreads();
    // segmented pool: thread (col, quarter) scans 16 sorted rows, one atomic per run
    {
        int col = tid & 127, quarter = tid >> 7;
        int rbeg = quarter * 16, rend = rbeg + 16;
        float run = 0.f; int curg = -1;
        for (int r = rbeg; r < rend; ++r) {
            int gg = sb[r];
            if (gg < 0) break;
            if (gg != curg) {
                if (curg >= 0) atomicAdd(&G[curg * 128 + col], run);
                run = 0.f; curg = gg;
            }
            run += bf2f(smZ[r * 128 + col]);
        }
        if (curg >= 0) atomicAdd(&G[curg * 128 + col], run);
    }
}

// ---------------- final FC: out = relu(g @ Wfc + bfc) ----------------
__global__ void k_fc(const float* __restrict__ G, const float* __restrict__ W,
                     const float* __restrict__ bias, float* __restrict__ O) {
    __shared__ float gs[128];
    int t = threadIdx.x, gidx = blockIdx.x;
    gs[t] = G[gidx * 128 + t];
    __syncthreads();
    float acc = bias[t];
    for (int k = 0; k < 128; ++k)
        acc += gs[k] * W[k * 128 + t];
    acc = acc > 0.f ? acc : 0.f;
    O[gidx * 128 + t] = acc;
}

extern "C" void kernel_launch(void* const* d_in, const int* in_sizes, int n_in,
                              void* d_out, int out_size, void* d_ws, size_t ws_size,
                              hipStream_t stream) {
    const int N = N_NODES, E = N_EDGES, NG = N_GRAPHS;

    const float* x   = (const float*)d_in[0];
    const int* ei    = (const int*)d_in[1];
    const int* batch = (const int*)d_in[2];
    const float* W1a = (const float*)d_in[3];
    const float* b1a = (const float*)d_in[4];
    const float* W1b = (const float*)d_in[5];
    const float* b1b = (const float*)d_in[6];
    const float* W2a = (const float*)d_in[7];
    const float* b2a = (const float*)d_in[8];
    const float* W2b = (const float*)d_in[9];
    const float* b2b = (const float*)d_in[10];
    const float* Wfc = (const float*)d_in[11];
    const float* bfc = (const float*)d_in[12];
    float* out = (float*)d_out;

    char* w = (char*)d_ws;
    int* cur    = (int*)(w + 0x0000000);   // 782 cursors, 128B apart -> 100KB
    float* g    = (float*)(w + 0x0019000); // 256KB — adjacent to cur: one memset
    u32* bins   = (u32*)(w + 0x0060000);   // 782 x 1536 x 4B = 4.6MB edge buckets
    u16* xb     = (u16*)(w + 0x0500000);   // 12.8MB + pad row (X in bf16)
    u16* hb     = (u16*)(w + 0x1200000);   // 12.8MB + pad row (H table)
    u16* T1a    = (u16*)(w + 0x1F00000);   // 32KB each
    u16* T1b    = (u16*)(w + 0x1F08000);
    u16* T2a    = (u16*)(w + 0x1F10000);
    u16* T2b    = (u16*)(w + 0x1F18000);

    (void)hipMemsetAsync(w, 0, 0x59000, stream);   // cur + g in one shot

    const int n8 = N * 128 / 8;              // 800000 16B-chunks
    const int PREPB = SCB + 782 + 64 + 1;    // scatter + convert(16B/thr) + transpose + pad
    k_prep<<<PREPB, 1024, 0, stream>>>(ei, cur, bins, x, xb, hb, W1a, W1b, W2a, W2b,
                                       T1a, T1b, T2a, T2b, E, n8);

    const int GINB = (N + 63) / 64;          // 782 blocks = buckets, 2/CU resident

    k_gin1<<<GINB, 512, 0, stream>>>(xb, cur, bins, T1a, b1a, T1b, b1b, hb, N);
    k_gin2<<<GINB, 512, 0, stream>>>(hb, cur, bins, T2a, b2a, T2b, b2b, batch, g, N);

    k_fc<<<NG, 128, 0, stream>>>(g, Wfc, bfc, out);
}